// Round 1
// baseline (442.205 us; speedup 1.0000x reference)
//
#include <hip/hip_runtime.h>
#include <stdint.h>

#define GRID_N (256*256*256)
#define MAXID 32
#define NCLS 13
#define NBINS ((MAXID+1)*NCLS)

// ws layout (bytes):
//   0     : int counts[33*13]  (429 ints) -- zeroed via memset of first 4096 B
//   4096  : int pano_lut[33]
//   8192  : int sem_lut[35]
//   16384 : uint8 grid0[GRID_N]   (16 MiB)

__global__ __launch_bounds__(256) void k_hist(const int* __restrict__ inst,
                                              const int* __restrict__ sem,
                                              int* __restrict__ counts) {
    __shared__ int sh[NBINS];
    for (int i = threadIdx.x; i < NBINS; i += blockDim.x) sh[i] = 0;
    __syncthreads();
    int tid = blockIdx.x * blockDim.x + threadIdx.x;
    int stride = gridDim.x * blockDim.x;
    const int n4 = GRID_N / 4;
    for (int i = tid; i < n4; i += stride) {
        int4 a = ((const int4*)inst)[i];
        int4 b = ((const int4*)sem)[i];
        atomicAdd(&sh[a.x * NCLS + b.x], 1);
        atomicAdd(&sh[a.y * NCLS + b.y], 1);
        atomicAdd(&sh[a.z * NCLS + b.z], 1);
        atomicAdd(&sh[a.w * NCLS + b.w], 1);
    }
    __syncthreads();
    for (int i = threadIdx.x; i < NBINS; i += blockDim.x) {
        int v = sh[i];
        if (v) atomicAdd(&counts[i], v);
    }
}

__global__ void k_luts(const int* __restrict__ counts,
                       const int* __restrict__ ids2d, int n2d,
                       int* __restrict__ pano_lut, int* __restrict__ sem_lut) {
    // single thread: tiny serial work, replicates reference semantics exactly
    if (threadIdx.x != 0 || blockIdx.x != 0) return;
    int hist[MAXID + 1];
    bool in2d[MAXID + 1];
    for (int i = 0; i <= MAXID; ++i) {
        int s = 0;
        for (int c = 0; c < NCLS; ++c) s += counts[i * NCLS + c];
        hist[i] = s;
        bool f = false;
        for (int k = 0; k < n2d; ++k) if (ids2d[k] + 1 == i) f = true;
        in2d[i] = f;
    }
    int zero_present = 0;
    for (int i = 0; i <= MAXID; ++i)
        if (hist[i] > 0 && !in2d[i]) zero_present = 1;

    int pano_ids[MAXID + 1];
    bool present[MAXID + 1];
    pano_lut[0] = 0;
    int rank = 0;
    for (int j = 1; j <= MAXID; ++j) {
        bool p = in2d[j] && (hist[j] > 0);
        present[j] = p;
        if (p) rank++;
        pano_ids[j] = p ? (rank - 1 + zero_present + 2) : 0;
        pano_lut[j] = pano_ids[j];
    }
    // majority label per id, cols {0,10,11} forced to -1, first max wins
    int sel[MAXID + 1];
    for (int j = 1; j <= MAXID; ++j) {
        int best = -2, bc = 0;
        for (int c = 0; c < NCLS; ++c) {
            int v = (c == 0 || c == 10 || c == 11) ? -1 : counts[j * NCLS + c];
            if (v > best) { best = v; bc = c; }
        }
        sel[j] = bc;
    }
    for (int i = 0; i < MAXID + 3; ++i) sem_lut[i] = 0;  // size 35
    sem_lut[1] = 10;   // WALL_ID -> WALL_CLASS
    sem_lut[2] = 11;   // FLOOR_ID -> FLOOR_CLASS
    // scatter AFTER wall/floor entries (matches reference order; duplicate
    // index 0 only ever gets value 0)
    for (int j = 1; j <= MAXID; ++j)
        sem_lut[pano_ids[j]] = present[j] ? sel[j] : 0;
}

__global__ __launch_bounds__(256) void k_grid0(const int* __restrict__ inst,
                                               const int* __restrict__ sem,
                                               const int* __restrict__ pano_lut,
                                               uint8_t* __restrict__ grid0) {
    __shared__ int lut[MAXID + 1];
    if (threadIdx.x <= MAXID) lut[threadIdx.x] = pano_lut[threadIdx.x];
    __syncthreads();
    int tid = blockIdx.x * blockDim.x + threadIdx.x;
    int stride = gridDim.x * blockDim.x;
    const int n4 = GRID_N / 4;
    for (int i = tid; i < n4; i += stride) {
        int4 a = ((const int4*)inst)[i];
        int4 b = ((const int4*)sem)[i];
        uchar4 o;
        o.x = (b.x == 11) ? 2 : ((b.x == 10) ? 1 : (uint8_t)lut[a.x]);
        o.y = (b.y == 11) ? 2 : ((b.y == 10) ? 1 : (uint8_t)lut[a.y]);
        o.z = (b.z == 11) ? 2 : ((b.z == 10) ? 1 : (uint8_t)lut[a.z]);
        o.w = (b.w == 11) ? 2 : ((b.w == 10) ? 1 : (uint8_t)lut[a.w]);
        ((uchar4*)grid0)[i] = o;
    }
}

__global__ __launch_bounds__(256) void k_nn(const float* __restrict__ geo,
                                            const uint8_t* __restrict__ grid0,
                                            const int* __restrict__ sem_lut,
                                            int* __restrict__ out_pano,
                                            int* __restrict__ out_sem) {
    __shared__ int slut[MAXID + 3];
    if (threadIdx.x < MAXID + 3) slut[threadIdx.x] = sem_lut[threadIdx.x];
    __syncthreads();
    int i = blockIdx.x * blockDim.x + threadIdx.x;
    if (i >= GRID_N) return;
    int p = (int)grid0[i];
    float g = geo[i];
    if (p == 0 && fabsf(g) <= 1.5f) {
        int x = i >> 16, y = (i >> 8) & 255, z = i & 255;
        int label = 0;
        // offsets dx,dy,dz in [-3,3) lexicographic (dx slowest), wraparound,
        // first positive neighbor wins (matches jnp.roll scan order)
        for (int dx = -3; dx < 3; ++dx) {
            int xb = ((x + dx) & 255) << 16;
            for (int dy = -3; dy < 3; ++dy) {
                int yb = xb | (((y + dy) & 255) << 8);
                #pragma unroll
                for (int dz = -3; dz < 3; ++dz) {
                    int v = (int)grid0[yb | ((z + dz) & 255)];
                    if (v > 0) { label = v; goto done; }
                }
            }
        }
        done:
        p = label;
    }
    out_pano[i] = p;
    out_sem[i] = slut[p];
}

extern "C" void kernel_launch(void* const* d_in, const int* in_sizes, int n_in,
                              void* d_out, int out_size, void* d_ws, size_t ws_size,
                              hipStream_t stream) {
    const float* geo  = (const float*)d_in[0];
    const int*   inst = (const int*)d_in[1];
    const int*   sem  = (const int*)d_in[2];
    const int*   ids2d = (const int*)d_in[3];
    const int    n2d = in_sizes[3];

    char* ws = (char*)d_ws;
    int* counts   = (int*)(ws);
    int* pano_lut = (int*)(ws + 4096);
    int* sem_lut  = (int*)(ws + 8192);
    uint8_t* grid0 = (uint8_t*)(ws + 16384);

    int* out_pano = (int*)d_out;
    int* out_sem  = out_pano + GRID_N;

    hipMemsetAsync(counts, 0, 4096, stream);
    k_hist<<<1024, 256, 0, stream>>>(inst, sem, counts);
    k_luts<<<1, 64, 0, stream>>>(counts, ids2d, n2d, pano_lut, sem_lut);
    k_grid0<<<4096, 256, 0, stream>>>(inst, sem, pano_lut, grid0);
    k_nn<<<GRID_N / 256, 256, 0, stream>>>(geo, grid0, sem_lut, out_pano, out_sem);
}

// Round 2
// 339.175 us; speedup vs baseline: 1.3038x; 1.3038x over previous
//
#include <hip/hip_runtime.h>
#include <stdint.h>

#define GRID_N (256*256*256)
#define MAXID 32
#define NCLS 13
#define NBINS ((MAXID+1)*NCLS)   // 429

// ws layout (bytes):
//   0     : int counts[429]          (zeroed via memset of first 4096 B)
//   4096  : int glut[34+35]          (grid0 lut over key 0..33, then sem_lut[35])
//   16384 : uint8 key[GRID_N]        (16 MiB: inst id, or 32=wall, 33=floor)

// ---------------------------------------------------------------- pass 1
// joint (inst,class) histogram + 1-byte key write (avoids re-reading
// inst+sem (134 MB) in a later pass; key is 16 MB).
__global__ __launch_bounds__(256) void k_prep(const int* __restrict__ inst,
                                              const int* __restrict__ sem,
                                              int* __restrict__ counts,
                                              uint8_t* __restrict__ key) {
    __shared__ int sh[NBINS];
    for (int i = threadIdx.x; i < NBINS; i += blockDim.x) sh[i] = 0;
    __syncthreads();
    int tid = blockIdx.x * blockDim.x + threadIdx.x;
    int stride = gridDim.x * blockDim.x;
    const int n4 = GRID_N / 4;
    for (int i = tid; i < n4; i += stride) {
        int4 a = ((const int4*)inst)[i];
        int4 b = ((const int4*)sem)[i];
        atomicAdd(&sh[a.x * NCLS + b.x], 1);
        atomicAdd(&sh[a.y * NCLS + b.y], 1);
        atomicAdd(&sh[a.z * NCLS + b.z], 1);
        atomicAdd(&sh[a.w * NCLS + b.w], 1);
        uchar4 k;
        k.x = (b.x == 11) ? 33 : ((b.x == 10) ? 32 : (uint8_t)a.x);
        k.y = (b.y == 11) ? 33 : ((b.y == 10) ? 32 : (uint8_t)a.y);
        k.z = (b.z == 11) ? 33 : ((b.z == 10) ? 32 : (uint8_t)a.z);
        k.w = (b.w == 11) ? 33 : ((b.w == 10) ? 32 : (uint8_t)a.w);
        ((uchar4*)key)[i] = k;
    }
    __syncthreads();
    for (int i = threadIdx.x; i < NBINS; i += blockDim.x) {
        int v = sh[i];
        if (v) atomicAdd(&counts[i], v);
    }
}

// ---------------------------------------------------------------- LUTs
// counts staged into LDS by 429 parallel threads (the round-1 version did
// ~430 SERIAL global loads from one thread -> latency disaster); the tiny
// serial logic then runs from LDS.
__global__ __launch_bounds__(512) void k_luts(const int* __restrict__ counts,
                                              const int* __restrict__ ids2d, int n2d,
                                              int* __restrict__ glut) {
    __shared__ int shc[NBINS];
    __shared__ int hist[MAXID + 1];
    __shared__ int in2d[MAXID + 1];
    __shared__ int sel[MAXID + 1];
    int t = threadIdx.x;
    if (t < NBINS) shc[t] = counts[t];
    __syncthreads();
    if (t <= MAXID) {
        int s = 0;
        for (int c = 0; c < NCLS; ++c) s += shc[t * NCLS + c];
        hist[t] = s;
        int f = 0;
        for (int k = 0; k < n2d; ++k) if (ids2d[k] + 1 == t) f = 1;
        in2d[t] = f;
        // majority label, cols {0,10,11} = -1, first max wins
        int best = -2, bc = 0;
        for (int c = 0; c < NCLS; ++c) {
            int v = (c == 0 || c == 10 || c == 11) ? -1 : shc[t * NCLS + c];
            if (v > best) { best = v; bc = c; }
        }
        sel[t] = bc;
    }
    __syncthreads();
    if (t == 0) {
        int zero_present = 0;
        for (int i = 0; i <= MAXID; ++i)
            if (hist[i] > 0 && !in2d[i]) zero_present = 1;
        int pano_ids[MAXID + 1];
        int present[MAXID + 1];
        glut[0] = 0;
        int rank = 0;
        for (int j = 1; j <= MAXID; ++j) {
            int p = in2d[j] && (hist[j] > 0);
            present[j] = p;
            if (p) rank++;
            pano_ids[j] = p ? (rank - 1 + zero_present + 2) : 0;
            if (j < 32) glut[j] = pano_ids[j];   // key 0..31 -> pano id
        }
        glut[32] = 1;   // wall key -> WALL_ID
        glut[33] = 2;   // floor key -> FLOOR_ID
        int* sem_lut = glut + 34;               // [35]
        for (int i = 0; i < MAXID + 3; ++i) sem_lut[i] = 0;
        sem_lut[1] = 10;
        sem_lut[2] = 11;
        for (int j = 1; j <= MAXID; ++j)
            sem_lut[pano_ids[j]] = present[j] ? sel[j] : 0;
    }
}

// ---------------------------------------------------------------- pass 2
// nn_search from an LDS halo tile. Block = 4x4x64 voxels (x,y,z); halo
// covers offsets [-3,2] in each dim. LDS tile is 9x9 rows of 72 bytes
// (z window z0-4 .. z0+67, dword aligned, wraparound folded in at fill).
// Tile bytes hold grid0 = lut(key), so probes are single LDS byte reads.
#define ROWB 72          // bytes per z-row in LDS (18 dwords)
#define NROWS 81         // 9*9
#define NDW (NROWS*18)   // 1458 dwords to fill

__global__ __launch_bounds__(256) void k_nn(const float* __restrict__ geo,
                                            const uint8_t* __restrict__ key,
                                            const int* __restrict__ glut,
                                            int* __restrict__ out_pano,
                                            int* __restrict__ out_sem) {
    __shared__ uint8_t sh_g[NROWS * ROWB];   // 5832 B, lut-applied grid0 tile
    __shared__ uint8_t sh_lut[64];           // key -> grid0 value
    __shared__ int slut[MAXID + 3];          // pano id -> semantic class

    int t = threadIdx.x;
    if (t < 34) sh_lut[t] = (uint8_t)glut[t];
    else if (t >= 64 && t < 64 + MAXID + 3) slut[t - 64] = glut[34 + (t - 64)];
    __syncthreads();

    int z0 = blockIdx.x * 64;
    int y0 = blockIdx.y * 4;
    int x0 = blockIdx.z * 4;

    const uint32_t* key32 = (const uint32_t*)key;
    uint32_t* shg32 = (uint32_t*)sh_g;
    for (int idx = t; idx < NDW; idx += 256) {
        int row = idx / 18;
        int k = idx - row * 18;
        int ix = row / 9;
        int iy = row - ix * 9;
        int gx = (x0 + ix - 3) & 255;
        int gy = (y0 + iy - 3) & 255;
        int gzd = ((z0 - 4 + (k << 2)) & 255) >> 2;
        uint32_t w = key32[(gx << 14) | (gy << 6) | gzd];
        uint32_t g = (uint32_t)sh_lut[w & 63]
                   | ((uint32_t)sh_lut[(w >> 8) & 63] << 8)
                   | ((uint32_t)sh_lut[(w >> 16) & 63] << 16)
                   | ((uint32_t)sh_lut[(w >> 24) & 63] << 24);
        shg32[idx] = g;
    }
    __syncthreads();

    int tz = t & 63;
    int ty = t >> 6;            // 0..3
    const uint32_t* shr32 = (const uint32_t*)sh_g;

    for (int tx = 0; tx < 4; ++tx) {
        int x = x0 + tx, y = y0 + ty, z = z0 + tz;
        int i = (x << 16) | (y << 8) | z;
        int p = sh_g[((tx + 3) * 9 + (ty + 3)) * ROWB + tz + 4];
        float g = geo[i];
        if (p == 0 && fabsf(g) <= 1.5f) {
            int label = 0;
            for (int dxi = 0; dxi < 6 && !label; ++dxi) {
                int rb = ((tx + dxi) * 9 + ty) * ROWB + tz + 1;
                for (int dyi = 0; dyi < 6; ++dyi) {
                    int zb = rb + dyi * ROWB;       // first of 6 probe bytes
                    int a = zb >> 2, off = zb & 3;
                    uint32_t d0 = shr32[a], d1 = shr32[a + 1], d2 = shr32[a + 2];
                    uint64_t lo = (uint64_t)d0 | ((uint64_t)d1 << 32);
                    uint64_t win = lo >> (off * 8);
                    if (off) win |= (uint64_t)d2 << (64 - off * 8);
                    uint64_t mask = win & 0x0000FFFFFFFFFFFFULL;  // 6 bytes, z order
                    if (mask) {
                        int b = __ffsll((long long)mask) - 1;     // lowest nonzero byte = first z
                        label = (int)((win >> (b & 56)) & 0xff);
                        break;
                    }
                }
            }
            p = label;
        }
        out_pano[i] = p;
        out_sem[i] = slut[p];
    }
}

extern "C" void kernel_launch(void* const* d_in, const int* in_sizes, int n_in,
                              void* d_out, int out_size, void* d_ws, size_t ws_size,
                              hipStream_t stream) {
    const float* geo   = (const float*)d_in[0];
    const int*   inst  = (const int*)d_in[1];
    const int*   sem   = (const int*)d_in[2];
    const int*   ids2d = (const int*)d_in[3];
    const int    n2d   = in_sizes[3];

    char* ws = (char*)d_ws;
    int* counts  = (int*)(ws);
    int* glut    = (int*)(ws + 4096);
    uint8_t* key = (uint8_t*)(ws + 16384);

    int* out_pano = (int*)d_out;
    int* out_sem  = out_pano + GRID_N;

    hipMemsetAsync(counts, 0, 4096, stream);
    k_prep<<<1024, 256, 0, stream>>>(inst, sem, counts, key);
    k_luts<<<1, 512, 0, stream>>>(counts, ids2d, n2d, glut);
    dim3 g(4, 64, 64);   // bz, by, bx
    k_nn<<<g, 256, 0, stream>>>(geo, key, glut, out_pano, out_sem);
}

// Round 3
// 308.968 us; speedup vs baseline: 1.4312x; 1.0978x over previous
//
#include <hip/hip_runtime.h>
#include <stdint.h>

#define GRID_N (256*256*256)
#define MAXID 32
#define NCLS 13
#define NBINS ((MAXID+1)*NCLS)   // 429

// ws layout (bytes):
//   0     : int counts[429]      (zeroed via memset of first 4096 B)
//   4096  : int glut[34+35]      (key->pano lut 0..33, then sem_lut[35])
//   16384 : uint8 key[GRID_N]    (16 MiB: bits 0..5 = inst id / 32=wall / 33=floor,
//                                 bit 6 = surface (|geo|<=1.5))

// ---------------------------------------------------------------- pass 1
// joint (inst,class) histogram + key byte (id/wall/floor + surface bit).
// geo is read HERE (streams at full BW) so k_nn never touches it.
__global__ __launch_bounds__(256) void k_prep(const float* __restrict__ geo,
                                              const int* __restrict__ inst,
                                              const int* __restrict__ sem,
                                              int* __restrict__ counts,
                                              uint8_t* __restrict__ key) {
    __shared__ int sh[2][NBINS];
    for (int i = threadIdx.x; i < 2 * NBINS; i += blockDim.x) sh[0][i] = 0;
    __syncthreads();
    int* myh = sh[(threadIdx.x >> 6) & 1];   // wave-parity sub-histogram
    int tid = blockIdx.x * blockDim.x + threadIdx.x;
    int stride = gridDim.x * blockDim.x;
    const int n4 = GRID_N / 4;
    for (int i = tid; i < n4; i += stride) {
        int4 a = ((const int4*)inst)[i];
        int4 b = ((const int4*)sem)[i];
        float4 g = ((const float4*)geo)[i];
        atomicAdd(&myh[a.x * NCLS + b.x], 1);
        atomicAdd(&myh[a.y * NCLS + b.y], 1);
        atomicAdd(&myh[a.z * NCLS + b.z], 1);
        atomicAdd(&myh[a.w * NCLS + b.w], 1);
        uchar4 k;
        k.x = ((b.x == 11) ? 33 : ((b.x == 10) ? 32 : (uint8_t)a.x)) | (fabsf(g.x) <= 1.5f ? 64 : 0);
        k.y = ((b.y == 11) ? 33 : ((b.y == 10) ? 32 : (uint8_t)a.y)) | (fabsf(g.y) <= 1.5f ? 64 : 0);
        k.z = ((b.z == 11) ? 33 : ((b.z == 10) ? 32 : (uint8_t)a.z)) | (fabsf(g.z) <= 1.5f ? 64 : 0);
        k.w = ((b.w == 11) ? 33 : ((b.w == 10) ? 32 : (uint8_t)a.w)) | (fabsf(g.w) <= 1.5f ? 64 : 0);
        ((uchar4*)key)[i] = k;
    }
    __syncthreads();
    for (int i = threadIdx.x; i < NBINS; i += blockDim.x) {
        int v = sh[0][i] + sh[1][i];
        if (v) atomicAdd(&counts[i], v);
    }
}

// ---------------------------------------------------------------- LUTs
__global__ __launch_bounds__(512) void k_luts(const int* __restrict__ counts,
                                              const int* __restrict__ ids2d, int n2d,
                                              int* __restrict__ glut) {
    __shared__ int shc[NBINS];
    __shared__ int hist[MAXID + 1];
    __shared__ int in2d[MAXID + 1];
    __shared__ int sel[MAXID + 1];
    int t = threadIdx.x;
    if (t < NBINS) shc[t] = counts[t];
    __syncthreads();
    if (t <= MAXID) {
        int s = 0;
        for (int c = 0; c < NCLS; ++c) s += shc[t * NCLS + c];
        hist[t] = s;
        int f = 0;
        for (int k = 0; k < n2d; ++k) if (ids2d[k] + 1 == t) f = 1;
        in2d[t] = f;
        int best = -2, bc = 0;
        for (int c = 0; c < NCLS; ++c) {
            int v = (c == 0 || c == 10 || c == 11) ? -1 : shc[t * NCLS + c];
            if (v > best) { best = v; bc = c; }
        }
        sel[t] = bc;
    }
    __syncthreads();
    if (t == 0) {
        int zero_present = 0;
        for (int i = 0; i <= MAXID; ++i)
            if (hist[i] > 0 && !in2d[i]) zero_present = 1;
        int pano_ids[MAXID + 1];
        int present[MAXID + 1];
        glut[0] = 0;
        int rank = 0;
        for (int j = 1; j <= MAXID; ++j) {
            int p = in2d[j] && (hist[j] > 0);
            present[j] = p;
            if (p) rank++;
            pano_ids[j] = p ? (rank - 1 + zero_present + 2) : 0;
            if (j < 32) glut[j] = pano_ids[j];
        }
        glut[32] = 1;   // wall
        glut[33] = 2;   // floor
        int* sem_lut = glut + 34;   // [35]
        for (int i = 0; i < MAXID + 3; ++i) sem_lut[i] = 0;
        sem_lut[1] = 10;
        sem_lut[2] = 11;
        for (int j = 1; j <= MAXID; ++j)
            sem_lut[pano_ids[j]] = present[j] ? sel[j] : 0;
    }
}

// ---------------------------------------------------------------- pass 2
// Tile = 8x8 (x,y) x full 256 z-line. LDS rows: 13x13 (x,y halo [-3,+2]
// around the 8-wide tile) x 264 bytes (z = -4..259 wrapped) -> all fill
// loads are 256B-contiguous per wave. Byte = grid0 | surface<<7.
#define TX 8
#define TY 8
#define HR 13              // TX+5
#define NROWS (HR*HR)      // 169
#define ROWDW 66           // 264 B per row
#define NDW (NROWS*ROWDW)  // 11154

__global__ __launch_bounds__(512) void k_nn(const uint8_t* __restrict__ key,
                                            const int* __restrict__ glut,
                                            int* __restrict__ out_pano,
                                            int* __restrict__ out_sem) {
    __shared__ uint32_t shg[NDW];     // 44616 B
    __shared__ int lut[128];          // key(7b incl surface) -> grid0 | surface<<7
    __shared__ int slut[MAXID + 3];

    int t = threadIdx.x;
    if (t < 128) {
        int base = ((t & 63) <= 33) ? glut[t & 63] : 0;
        lut[t] = base | ((t & 64) << 1);
    } else if (t >= 128 && t < 128 + MAXID + 3) {
        slut[t - 128] = glut[34 + (t - 128)];
    }
    __syncthreads();

    int x0 = blockIdx.x * TX;
    int y0 = blockIdx.y * TY;

    const uint32_t* key32 = (const uint32_t*)key;
    for (int idx = t; idx < NDW; idx += 512) {
        int row = idx / ROWDW;
        int k = idx - row * ROWDW;
        int ix = row / HR;
        int iy = row - ix * HR;
        int gx = (x0 + ix - 3) & 255;
        int gy = (y0 + iy - 3) & 255;
        uint32_t w = key32[(gx << 14) | (gy << 6) | ((k - 1) & 63)];
        shg[idx] = (uint32_t)lut[w & 127]
                 | ((uint32_t)lut[(w >> 8) & 127] << 8)
                 | ((uint32_t)lut[(w >> 16) & 127] << 16)
                 | ((uint32_t)lut[(w >> 24) & 127] << 24);
    }
    __syncthreads();

    int zg = t & 63;          // z-group: z = 4*zg .. 4*zg+3
    int ty = t >> 6;          // 0..7
    int gy = y0 + ty;
    const uint64_t M6 = 0x00007F7F7F7F7F7FULL;

    for (int x = 0; x < TX; ++x) {
        int gx = x0 + x;
        int r0 = (x + 3) * HR + (ty + 3);
        uint32_t cw = shg[r0 * ROWDW + zg + 1];   // 4 center bytes (z=4zg..+3)
        int4 pano, semv;
        int pv[4];
        #pragma unroll
        for (int b = 0; b < 4; ++b) {
            int v = (cw >> (8 * b)) & 255;
            int p = v & 127;
            if (p == 0 && (v & 128)) {
                int z = 4 * zg + b;
                int label = 0;
                int j0 = z + 1;
                int a0 = j0 >> 2, off = j0 & 3;
                for (int dxi = 0; dxi < 6 && !label; ++dxi) {
                    int rb = ((x + dxi) * HR + ty) * ROWDW + a0;
                    for (int dyi = 0; dyi < 6; ++dyi) {
                        int a = rb + dyi * ROWDW;
                        uint32_t d0 = shg[a], d1 = shg[a + 1], d2 = shg[a + 2];
                        uint64_t lo = (uint64_t)d0 | ((uint64_t)d1 << 32);
                        uint64_t win = lo >> (off * 8);
                        if (off) win |= (uint64_t)d2 << (64 - off * 8);
                        uint64_t mask = win & M6;   // 6 bytes, surface bit stripped
                        if (mask) {
                            int bb = __ffsll((long long)mask) - 1;
                            label = (int)((win >> (bb & 56)) & 0x7f);
                            break;
                        }
                    }
                }
                p = label;
            }
            pv[b] = p;
        }
        pano.x = pv[0]; pano.y = pv[1]; pano.z = pv[2]; pano.w = pv[3];
        semv.x = slut[pv[0]]; semv.y = slut[pv[1]]; semv.z = slut[pv[2]]; semv.w = slut[pv[3]];
        int oi = (gx << 14) | (gy << 6) | zg;     // int4 index
        ((int4*)out_pano)[oi] = pano;
        ((int4*)out_sem)[oi] = semv;
    }
}

extern "C" void kernel_launch(void* const* d_in, const int* in_sizes, int n_in,
                              void* d_out, int out_size, void* d_ws, size_t ws_size,
                              hipStream_t stream) {
    const float* geo   = (const float*)d_in[0];
    const int*   inst  = (const int*)d_in[1];
    const int*   sem   = (const int*)d_in[2];
    const int*   ids2d = (const int*)d_in[3];
    const int    n2d   = in_sizes[3];

    char* ws = (char*)d_ws;
    int* counts  = (int*)(ws);
    int* glut    = (int*)(ws + 4096);
    uint8_t* key = (uint8_t*)(ws + 16384);

    int* out_pano = (int*)d_out;
    int* out_sem  = out_pano + GRID_N;

    hipMemsetAsync(counts, 0, 4096, stream);
    k_prep<<<1024, 256, 0, stream>>>(geo, inst, sem, counts, key);
    k_luts<<<1, 512, 0, stream>>>(counts, ids2d, n2d, glut);
    dim3 g(32, 32);
    k_nn<<<g, 512, 0, stream>>>(key, glut, out_pano, out_sem);
}

// Round 4
// 305.851 us; speedup vs baseline: 1.4458x; 1.0102x over previous
//
#include <hip/hip_runtime.h>
#include <stdint.h>

#define GRID_N (256*256*256)
#define MAXID 32
#define NCLS 13
#define NBINS ((MAXID+1)*NCLS)   // 429
#define PREP_BLOCKS 4096

// ws layout (bytes):
//   0     : int counts8[8][429]  (13728 B, zeroed via memset of first 16384 B)
//   16384 : int glut[34+35]      (key->pano lut 0..33, then sem_lut[35])
//   32768 : uint8 key[GRID_N]    (16 MiB: bits 0..5 = inst id / 32=wall / 33=floor,
//                                 bit 6 = surface (|geo|<=1.5))

__device__ __forceinline__ uint8_t keyb(int a, int b, float g) {
    int k = (b == 11) ? 33 : ((b == 10) ? 32 : a);
    return (uint8_t)(k | ((fabsf(g) <= 1.5f) ? 64 : 0));
}

// ---------------------------------------------------------------- pass 1
// Joint (inst,class) histogram + key byte. Fully unrolled 4 iterations with
// all 12 dwordx4 loads issued up front (latency was the round-3 bottleneck:
// 17% HBM, 6% VALU, 39% occupancy). Per-wave LDS sub-histograms; flush to
// 8-way banked global counts to cut same-address atomic chains.
__global__ __launch_bounds__(256, 4) void k_prep(const float* __restrict__ geo,
                                                 const int* __restrict__ inst,
                                                 const int* __restrict__ sem,
                                                 int* __restrict__ counts8,
                                                 uint8_t* __restrict__ key) {
    __shared__ int sh[4][NBINS];
    int t = threadIdx.x;
    for (int i = t; i < 4 * NBINS; i += 256) ((int*)sh)[i] = 0;
    __syncthreads();
    int* myh = sh[t >> 6];

    const int stride = PREP_BLOCKS * 256;            // 1048576 int4s
    int base = blockIdx.x * 256 + t;
    const int4*  i4 = (const int4*)inst;
    const int4*  s4 = (const int4*)sem;
    const float4* g4 = (const float4*)geo;

    int4 a0 = i4[base],            a1 = i4[base + stride],
         a2 = i4[base + 2*stride], a3 = i4[base + 3*stride];
    int4 b0 = s4[base],            b1 = s4[base + stride],
         b2 = s4[base + 2*stride], b3 = s4[base + 3*stride];
    float4 g0 = g4[base],            g1 = g4[base + stride],
           g2 = g4[base + 2*stride], g3 = g4[base + 3*stride];

    uchar4* k4 = (uchar4*)key;
    #define DOIT(A,B,G,IDX)                                                  \
        atomicAdd(&myh[(A).x * NCLS + (B).x], 1);                            \
        atomicAdd(&myh[(A).y * NCLS + (B).y], 1);                            \
        atomicAdd(&myh[(A).z * NCLS + (B).z], 1);                            \
        atomicAdd(&myh[(A).w * NCLS + (B).w], 1);                            \
        { uchar4 kk; kk.x = keyb((A).x,(B).x,(G).x);                         \
          kk.y = keyb((A).y,(B).y,(G).y); kk.z = keyb((A).z,(B).z,(G).z);    \
          kk.w = keyb((A).w,(B).w,(G).w); k4[IDX] = kk; }
    DOIT(a0,b0,g0,base)
    DOIT(a1,b1,g1,base + stride)
    DOIT(a2,b2,g2,base + 2*stride)
    DOIT(a3,b3,g3,base + 3*stride)
    #undef DOIT

    __syncthreads();
    int* dst = counts8 + (blockIdx.x & 7) * NBINS;
    for (int i = t; i < NBINS; i += 256) {
        int v = sh[0][i] + sh[1][i] + sh[2][i] + sh[3][i];
        if (v) atomicAdd(&dst[i], v);
    }
}

// ---------------------------------------------------------------- LUTs
// Stage 8-way counts into LDS (parallel), then wave 0 does everything with
// ballot/popcount parallelism (round-3 version had ~100 SERIAL global ops
// in thread 0). Final LUT written with one parallel global store.
__global__ __launch_bounds__(512) void k_luts(const int* __restrict__ counts8,
                                              const int* __restrict__ ids2d, int n2d,
                                              int* __restrict__ glut) {
    __shared__ int shc[NBINS];
    __shared__ int sem_s[35];
    int t = threadIdx.x;
    if (t < NBINS) {
        int s = 0;
        #pragma unroll
        for (int c = 0; c < 8; ++c) s += counts8[c * NBINS + t];
        shc[t] = s;
    }
    __syncthreads();
    if (t < 64) {
        int hist_t = 0, in2d_t = 0, sel_t = 0;
        if (t <= MAXID) {
            for (int c = 0; c < NCLS; ++c) hist_t += shc[t * NCLS + c];
            for (int k = 0; k < n2d; ++k) if (ids2d[k] + 1 == t) in2d_t = 1;
            int best = -2;
            for (int c = 0; c < NCLS; ++c) {
                int v = (c == 0 || c == 10 || c == 11) ? -1 : shc[t * NCLS + c];
                if (v > best) { best = v; sel_t = c; }
            }
        }
        unsigned long long zm = __ballot(t <= MAXID && hist_t > 0 && !in2d_t);
        int zero_present = (zm != 0ULL) ? 1 : 0;
        int pres = (t >= 1 && t <= MAXID && in2d_t && hist_t > 0) ? 1 : 0;
        unsigned long long pm = __ballot(pres);
        int rank_below = __popcll(pm & ((1ULL << t) - 1ULL));
        int pano_id = pres ? (rank_below + zero_present + 2) : 0;

        if (t < 35) sem_s[t] = (t == 1) ? 10 : ((t == 2) ? 11 : 0);
        if (pres) sem_s[pano_id] = sel_t;       // disjoint pano_ids; after defaults

        if (t < 32) glut[t] = (t == 0) ? 0 : pano_id;   // key id -> pano id
        if (t == 32) glut[32] = 1;                      // wall
        if (t == 33) glut[33] = 2;                      // floor
        if (t < 35) glut[34 + t] = sem_s[t];            // sem_lut
    }
}

// ---------------------------------------------------------------- pass 2
// Tile = 8x8 (x,y) x full 256 z-line. LDS rows: 13x13 (x,y halo [-3,+2])
// x 264 bytes (z = -4..259 wrapped). Byte = grid0 | surface<<7.
#define TX 8
#define TY 8
#define HR 13              // TX+5
#define NROWS (HR*HR)      // 169
#define ROWDW 66           // 264 B per row
#define NDW (NROWS*ROWDW)  // 11154

__global__ __launch_bounds__(512) void k_nn(const uint8_t* __restrict__ key,
                                            const int* __restrict__ glut,
                                            int* __restrict__ out_pano,
                                            int* __restrict__ out_sem) {
    __shared__ uint32_t shg[NDW];     // 44616 B
    __shared__ int lut[128];          // key(7b incl surface) -> grid0 | surface<<7
    __shared__ int slut[MAXID + 3];

    int t = threadIdx.x;
    if (t < 128) {
        int base = ((t & 63) <= 33) ? glut[t & 63] : 0;
        lut[t] = base | ((t & 64) << 1);
    } else if (t >= 128 && t < 128 + MAXID + 3) {
        slut[t - 128] = glut[34 + (t - 128)];
    }
    __syncthreads();

    int x0 = blockIdx.x * TX;
    int y0 = blockIdx.y * TY;

    const uint32_t* key32 = (const uint32_t*)key;
    for (int idx = t; idx < NDW; idx += 512) {
        int row = idx / ROWDW;
        int k = idx - row * ROWDW;
        int ix = row / HR;
        int iy = row - ix * HR;
        int gx = (x0 + ix - 3) & 255;
        int gy = (y0 + iy - 3) & 255;
        uint32_t w = key32[(gx << 14) | (gy << 6) | ((k - 1) & 63)];
        shg[idx] = (uint32_t)lut[w & 127]
                 | ((uint32_t)lut[(w >> 8) & 127] << 8)
                 | ((uint32_t)lut[(w >> 16) & 127] << 16)
                 | ((uint32_t)lut[(w >> 24) & 127] << 24);
    }
    __syncthreads();

    int zg = t & 63;          // z-group: z = 4*zg .. 4*zg+3
    int ty = t >> 6;          // 0..7
    int gy = y0 + ty;
    const uint64_t M6 = 0x00007F7F7F7F7F7FULL;

    for (int x = 0; x < TX; ++x) {
        int gx = x0 + x;
        int r0 = (x + 3) * HR + (ty + 3);
        uint32_t cw = shg[r0 * ROWDW + zg + 1];   // 4 center bytes (z=4zg..+3)
        int4 pano, semv;
        int pv[4];
        #pragma unroll
        for (int b = 0; b < 4; ++b) {
            int v = (cw >> (8 * b)) & 255;
            int p = v & 127;
            if (p == 0 && (v & 128)) {
                int z = 4 * zg + b;
                int label = 0;
                int j0 = z + 1;
                int a0 = j0 >> 2, off = j0 & 3;
                for (int dxi = 0; dxi < 6 && !label; ++dxi) {
                    int rb = ((x + dxi) * HR + ty) * ROWDW + a0;
                    for (int dyi = 0; dyi < 6; ++dyi) {
                        int a = rb + dyi * ROWDW;
                        uint32_t d0 = shg[a], d1 = shg[a + 1], d2 = shg[a + 2];
                        uint64_t lo = (uint64_t)d0 | ((uint64_t)d1 << 32);
                        uint64_t win = lo >> (off * 8);
                        if (off) win |= (uint64_t)d2 << (64 - off * 8);
                        uint64_t mask = win & M6;   // 6 bytes, surface bit stripped
                        if (mask) {
                            int bb = __ffsll((long long)mask) - 1;
                            label = (int)((win >> (bb & 56)) & 0x7f);
                            break;
                        }
                    }
                }
                p = label;
            }
            pv[b] = p;
        }
        pano.x = pv[0]; pano.y = pv[1]; pano.z = pv[2]; pano.w = pv[3];
        semv.x = slut[pv[0]]; semv.y = slut[pv[1]]; semv.z = slut[pv[2]]; semv.w = slut[pv[3]];
        int oi = (gx << 14) | (gy << 6) | zg;     // int4 index
        ((int4*)out_pano)[oi] = pano;
        ((int4*)out_sem)[oi] = semv;
    }
}

extern "C" void kernel_launch(void* const* d_in, const int* in_sizes, int n_in,
                              void* d_out, int out_size, void* d_ws, size_t ws_size,
                              hipStream_t stream) {
    const float* geo   = (const float*)d_in[0];
    const int*   inst  = (const int*)d_in[1];
    const int*   sem   = (const int*)d_in[2];
    const int*   ids2d = (const int*)d_in[3];
    const int    n2d   = in_sizes[3];

    char* ws = (char*)d_ws;
    int* counts8 = (int*)(ws);
    int* glut    = (int*)(ws + 16384);
    uint8_t* key = (uint8_t*)(ws + 32768);

    int* out_pano = (int*)d_out;
    int* out_sem  = out_pano + GRID_N;

    hipMemsetAsync(counts8, 0, 16384, stream);
    k_prep<<<PREP_BLOCKS, 256, 0, stream>>>(geo, inst, sem, counts8, key);
    k_luts<<<1, 512, 0, stream>>>(counts8, ids2d, n2d, glut);
    dim3 g(32, 32);
    k_nn<<<g, 512, 0, stream>>>(key, glut, out_pano, out_sem);
}